// Round 2
// baseline (843.458 us; speedup 1.0000x reference)
//
#include <hip/hip_runtime.h>
#include <hip/hip_bf16.h>
#include <math.h>

// Problem: B x B sim matrix (fp32), B = 8192.
// out[0..B)    = uncertainty
// out[B..2B)   = normalized_entropy
constexpr int BB = 8192;
constexpr float INV_MAX_ENT = 1.0f / 9.010913347279288f;  // 1/log(8192+1e-10)

// ---------------------------------------------------------------------------
// Kernel A: one block per row. Entropy of softmax(row*50) + top-10 col indices.
// Row held in registers: 256 threads x 32 floats (loaded as float4).
// col index mapping: x[i4*4+j] = row[ i4*1024 + t*4 + j ]
// ---------------------------------------------------------------------------
__global__ __launch_bounds__(256) void rows_kernel(const float* __restrict__ sim,
                                                   float* __restrict__ out,
                                                   int* __restrict__ row_top) {
  const int row = blockIdx.x;
  const int t = threadIdx.x;
  const int lane = t & 63;
  const int wid = t >> 6;

  const float4* __restrict__ r4 =
      reinterpret_cast<const float4*>(sim + (size_t)row * BB);

  float x[32];
#pragma unroll
  for (int i4 = 0; i4 < 8; ++i4) {
    float4 v = r4[t + (i4 << 8)];
    x[i4 * 4 + 0] = v.x;
    x[i4 * 4 + 1] = v.y;
    x[i4 * 4 + 2] = v.z;
    x[i4 * 4 + 3] = v.w;
  }

  // ---- row max ----
  float m = x[0];
#pragma unroll
  for (int i = 1; i < 32; ++i) m = fmaxf(m, x[i]);
#pragma unroll
  for (int off = 32; off > 0; off >>= 1) m = fmaxf(m, __shfl_xor(m, off));
  __shared__ float smax[4];
  if (lane == 0) smax[wid] = m;
  __syncthreads();
  m = fmaxf(fmaxf(smax[0], smax[1]), fmaxf(smax[2], smax[3]));

  // ---- S = sum exp(50x - 50m), W = sum e*d ----
  const float tm = 50.0f * m;
  float S = 0.0f, W = 0.0f;
#pragma unroll
  for (int i = 0; i < 32; ++i) {
    float d = fmaf(50.0f, x[i], -tm);   // <= 0
    float e = __expf(d);
    S += e;
    W += e * d;
  }
#pragma unroll
  for (int off = 32; off > 0; off >>= 1) {
    S += __shfl_xor(S, off);
    W += __shfl_xor(W, off);
  }
  __shared__ float sS[4], sW[4];
  if (lane == 0) { sS[wid] = S; sW[wid] = W; }
  __syncthreads();
  S = sS[0] + sS[1] + sS[2] + sS[3];
  W = sW[0] + sW[1] + sW[2] + sW[3];
  if (t == 0) {
    float ent = __logf(S) - W / S;   // -sum p log p  (eps term <= 8e-7, ignored)
    out[BB + row] = ent * INV_MAX_ENT;
  }

  // ---- top-10 by iterative block argmax ----
  __shared__ float swv[4];
  __shared__ int swc[4];
#pragma unroll 1
  for (int kk = 0; kk < 10; ++kk) {
    // per-thread argmax (first occurrence wins -> lowest col index on tie)
    float bv = x[0];
    int bc = (t << 2);  // col of x[0]
#pragma unroll
    for (int i4 = 0; i4 < 8; ++i4) {
#pragma unroll
      for (int j = 0; j < 4; ++j) {
        float v = x[i4 * 4 + j];
        int cc = (i4 << 10) + (t << 2) + j;
        if (v > bv) { bv = v; bc = cc; }
      }
    }
    // wave argmax, tie -> lower col
#pragma unroll
    for (int off = 32; off > 0; off >>= 1) {
      float ov = __shfl_xor(bv, off);
      int oc = __shfl_xor(bc, off);
      if (ov > bv || (ov == bv && oc < bc)) { bv = ov; bc = oc; }
    }
    if (lane == 0) { swv[wid] = bv; swc[wid] = bc; }
    __syncthreads();
    float fv = swv[0];
    int fc = swc[0];
#pragma unroll
    for (int w = 1; w < 4; ++w) {
      if (swv[w] > fv || (swv[w] == fv && swc[w] < fc)) { fv = swv[w]; fc = swc[w]; }
    }
    // winning thread masks out its element (static indices only)
    if (((fc >> 2) & 255) == t) {
      int li = ((fc >> 10) << 2) | (fc & 3);
#pragma unroll
      for (int i = 0; i < 32; ++i)
        if (i == li) x[i] = -INFINITY;
    }
    if (t == 0) row_top[row * 10 + kk] = fc;
    __syncthreads();
  }
}

// ---------------------------------------------------------------------------
// Kernel B: partial column top-10 over a chunk of rows.
// grid = (BB/256, nch); thread owns one column, streams CH rows (coalesced).
// ---------------------------------------------------------------------------
__global__ __launch_bounds__(256) void cols_partial_kernel(const float* __restrict__ sim,
                                                           float* __restrict__ pv,
                                                           int* __restrict__ pi,
                                                           int CH) {
  const int col = blockIdx.x * 256 + threadIdx.x;
  const int r0 = blockIdx.y * CH;

  float tv[10];
  int ti[10];
#pragma unroll
  for (int j = 0; j < 10; ++j) { tv[j] = -INFINITY; ti[j] = -1; }

  const float* __restrict__ p = sim + (size_t)r0 * BB + col;

#define INSERT_CAND(vv, id)                                   \
  if ((vv) > tv[9]) {                                         \
    float _v = (vv);                                          \
    int _i = (id);                                            \
    _Pragma("unroll") for (int j = 0; j < 10; ++j) {          \
      if (_v > tv[j]) {                                       \
        float _tv = tv[j]; tv[j] = _v; _v = _tv;              \
        int _ti = ti[j]; ti[j] = _i; _i = _ti;                \
      }                                                       \
    }                                                         \
  }

  for (int rr = 0; rr < CH; rr += 4) {
    float v0 = p[(size_t)(rr + 0) * BB];
    float v1 = p[(size_t)(rr + 1) * BB];
    float v2 = p[(size_t)(rr + 2) * BB];
    float v3 = p[(size_t)(rr + 3) * BB];
    INSERT_CAND(v0, r0 + rr + 0);
    INSERT_CAND(v1, r0 + rr + 1);
    INSERT_CAND(v2, r0 + rr + 2);
    INSERT_CAND(v3, r0 + rr + 3);
  }

  size_t base = ((size_t)blockIdx.y * BB + col) * 10;
#pragma unroll
  for (int j = 0; j < 10; ++j) {
    pv[base + j] = tv[j];
    pi[base + j] = ti[j];
  }
}

// ---------------------------------------------------------------------------
// Kernel C: merge partial column top-10 lists, count overlap with row top-10,
// write uncertainty. One thread per column.
// ---------------------------------------------------------------------------
__global__ __launch_bounds__(256) void merge_kernel(const float* __restrict__ pv,
                                                    const int* __restrict__ pi,
                                                    const int* __restrict__ row_top,
                                                    float* __restrict__ out,
                                                    int nch) {
  const int c = blockIdx.x * 256 + threadIdx.x;

  float tv[10];
  int ti[10];
#pragma unroll
  for (int j = 0; j < 10; ++j) { tv[j] = -INFINITY; ti[j] = -2; }

  for (int ch = 0; ch < nch; ++ch) {
    size_t base = ((size_t)ch * BB + c) * 10;
    for (int j = 0; j < 10; ++j) {         // list is sorted descending
      float v = pv[base + j];
      if (!(v > tv[9])) break;             // rest of this list can't qualify
      int id = pi[base + j];
      INSERT_CAND(v, id);
    }
  }

  int cnt = 0;
#pragma unroll 1
  for (int i2 = 0; i2 < 10; ++i2) {
    int rt = row_top[c * 10 + i2];
#pragma unroll
    for (int j = 0; j < 10; ++j) cnt += (rt == ti[j]) ? 1 : 0;
  }
  float ne = out[BB + c];
  float ra = (float)cnt / 10.0f;
  out[c] = (1.0f - ra) * 0.5f + 0.5f * ne;
}

#undef INSERT_CAND

// ---------------------------------------------------------------------------
extern "C" void kernel_launch(void* const* d_in, const int* in_sizes, int n_in,
                              void* d_out, int out_size, void* d_ws, size_t ws_size,
                              hipStream_t stream) {
  const float* sim = (const float*)d_in[0];
  float* out = (float*)d_out;

  // Workspace layout: row_top [BB*10 int] | pv [nch*BB*10 f32] | pi [nch*BB*10 int]
  int nch = 32;
  while (nch > 1) {
    size_t need = (size_t)BB * 10 * 4 + (size_t)nch * BB * 10 * 8;
    if (need <= ws_size) break;
    nch >>= 1;
  }
  int* row_top = (int*)d_ws;
  float* pv = (float*)((char*)d_ws + (size_t)BB * 10 * 4);
  int* pi = (int*)((char*)pv + (size_t)nch * BB * 10 * 4);

  rows_kernel<<<BB, 256, 0, stream>>>(sim, out, row_top);
  dim3 gb(BB / 256, nch);
  cols_partial_kernel<<<gb, 256, 0, stream>>>(sim, pv, pi, BB / nch);
  merge_kernel<<<BB / 256, 256, 0, stream>>>(pv, pi, row_top, out, nch);
}

// Round 4
// 572.317 us; speedup vs baseline: 1.4738x; 1.4738x over previous
//
#include <hip/hip_runtime.h>
#include <hip/hip_bf16.h>
#include <math.h>

// B x B fp32 sim matrix, B = 8192.
// out[0..B) = uncertainty, out[B..2B) = normalized_entropy
constexpr int BB = 8192;
constexpr float INV_MAX_ENT = 1.0f / 9.010913347279288f;  // 1/log(8192+1e-10)

// ---------------------------------------------------------------------------
// Kernel A: one block per row. Entropy of softmax(row*50) + top-10 col indices.
// Row held in registers: 256 threads x 32 floats (float4 loads).
// row_top layout: row_top[kk*BB + row]  (coalesced for merge)
// ---------------------------------------------------------------------------
__global__ __launch_bounds__(256) void rows_kernel(const float* __restrict__ sim,
                                                   float* __restrict__ out,
                                                   int* __restrict__ row_top) {
  const int row = blockIdx.x;
  const int t = threadIdx.x;
  const int lane = t & 63;
  const int wid = t >> 6;

  const float4* __restrict__ r4 =
      reinterpret_cast<const float4*>(sim + (size_t)row * BB);

  float x[32];
#pragma unroll
  for (int i4 = 0; i4 < 8; ++i4) {
    float4 v = r4[t + (i4 << 8)];
    x[i4 * 4 + 0] = v.x;
    x[i4 * 4 + 1] = v.y;
    x[i4 * 4 + 2] = v.z;
    x[i4 * 4 + 3] = v.w;
  }

  // ---- row max ----
  float m = x[0];
#pragma unroll
  for (int i = 1; i < 32; ++i) m = fmaxf(m, x[i]);
#pragma unroll
  for (int off = 32; off > 0; off >>= 1) m = fmaxf(m, __shfl_xor(m, off));
  __shared__ float smax[4];
  if (lane == 0) smax[wid] = m;
  __syncthreads();
  m = fmaxf(fmaxf(smax[0], smax[1]), fmaxf(smax[2], smax[3]));

  // ---- S = sum exp(50x - 50m), W = sum e*d ----
  const float tm = 50.0f * m;
  float S = 0.0f, W = 0.0f;
#pragma unroll
  for (int i = 0; i < 32; ++i) {
    float d = fmaf(50.0f, x[i], -tm);   // <= 0
    float e = __expf(d);
    S += e;
    W += e * d;
  }
#pragma unroll
  for (int off = 32; off > 0; off >>= 1) {
    S += __shfl_xor(S, off);
    W += __shfl_xor(W, off);
  }
  __shared__ float sS[4], sW[4];
  if (lane == 0) { sS[wid] = S; sW[wid] = W; }
  __syncthreads();
  S = sS[0] + sS[1] + sS[2] + sS[3];
  W = sW[0] + sW[1] + sW[2] + sW[3];
  if (t == 0) {
    float ent = __logf(S) - W / S;   // eps term <= 8e-7, ignored
    out[BB + row] = ent * INV_MAX_ENT;
  }

  // ---- top-10 by iterative block argmax ----
  __shared__ float swv[4];
  __shared__ int swc[4];
#pragma unroll 1
  for (int kk = 0; kk < 10; ++kk) {
    float bv = x[0];
    int bc = (t << 2);
#pragma unroll
    for (int i4 = 0; i4 < 8; ++i4) {
#pragma unroll
      for (int j = 0; j < 4; ++j) {
        float v = x[i4 * 4 + j];
        int cc = (i4 << 10) + (t << 2) + j;
        if (v > bv) { bv = v; bc = cc; }
      }
    }
#pragma unroll
    for (int off = 32; off > 0; off >>= 1) {
      float ov = __shfl_xor(bv, off);
      int oc = __shfl_xor(bc, off);
      if (ov > bv || (ov == bv && oc < bc)) { bv = ov; bc = oc; }
    }
    if (lane == 0) { swv[wid] = bv; swc[wid] = bc; }
    __syncthreads();
    float fv = swv[0];
    int fc = swc[0];
#pragma unroll
    for (int w = 1; w < 4; ++w) {
      if (swv[w] > fv || (swv[w] == fv && swc[w] < fc)) { fv = swv[w]; fc = swc[w]; }
    }
    if (((fc >> 2) & 255) == t) {
      int li = ((fc >> 10) << 2) | (fc & 3);
#pragma unroll
      for (int i = 0; i < 32; ++i)
        if (i == li) x[i] = -INFINITY;
    }
    if (t == 0) row_top[kk * BB + row] = fc;
    __syncthreads();
  }
}

// ---------------------------------------------------------------------------
// Named-register sorted top-10 insert (NO arrays -> no scratch, rule #20).
// Keeps lowest-index-first among equal values (strict >).
// ---------------------------------------------------------------------------
#define CAS_STEP(tvk, tik)                                  \
  if (v > tvk) {                                            \
    float _fv = tvk; tvk = v; v = _fv;                      \
    int _fi = tik; tik = id; id = _fi;                      \
  }

#define INS10(vv, ii)                                       \
  if ((vv) > tv9) {                                         \
    float v = (vv);                                         \
    int id = (ii);                                          \
    CAS_STEP(tv0, ti0) CAS_STEP(tv1, ti1)                   \
    CAS_STEP(tv2, ti2) CAS_STEP(tv3, ti3)                   \
    CAS_STEP(tv4, ti4) CAS_STEP(tv5, ti5)                   \
    CAS_STEP(tv6, ti6) CAS_STEP(tv7, ti7)                   \
    CAS_STEP(tv8, ti8) CAS_STEP(tv9, ti9)                   \
  }

#define DECL10                                              \
  float tv0 = -INFINITY, tv1 = -INFINITY, tv2 = -INFINITY,  \
        tv3 = -INFINITY, tv4 = -INFINITY, tv5 = -INFINITY,  \
        tv6 = -INFINITY, tv7 = -INFINITY, tv8 = -INFINITY,  \
        tv9 = -INFINITY;                                    \
  int ti0 = -1, ti1 = -1, ti2 = -1, ti3 = -1, ti4 = -1,     \
      ti5 = -1, ti6 = -1, ti7 = -1, ti8 = -1, ti9 = -1;

// ---------------------------------------------------------------------------
// Kernel B: partial column top-10 over a chunk of rows.
// grid = (BB/256, nch); thread owns one column, streams CH rows (coalesced).
// Partial layout: pv[(ch*10 + j)*BB + col]  (coalesced for merge)
// ---------------------------------------------------------------------------
__global__ __launch_bounds__(256) void cols_partial_kernel(const float* __restrict__ sim,
                                                           float* __restrict__ pv,
                                                           int* __restrict__ pi,
                                                           int CH) {
  const int col = blockIdx.x * 256 + threadIdx.x;
  const int r0 = blockIdx.y * CH;

  DECL10;

  const float* __restrict__ p = sim + (size_t)r0 * BB + col;

  for (int rr = 0; rr < CH; rr += 4) {
    float v0 = p[0];
    float v1 = p[BB];
    float v2 = p[2 * BB];
    float v3 = p[3 * BB];
    p += (size_t)4 * BB;
    INS10(v0, r0 + rr + 0);
    INS10(v1, r0 + rr + 1);
    INS10(v2, r0 + rr + 2);
    INS10(v3, r0 + rr + 3);
  }

  float* __restrict__ pvb = pv + (size_t)blockIdx.y * 10 * BB + col;
  int* __restrict__ pib = pi + (size_t)blockIdx.y * 10 * BB + col;
  pvb[0 * BB] = tv0;  pib[0 * BB] = ti0;
  pvb[1 * BB] = tv1;  pib[1 * BB] = ti1;
  pvb[2 * BB] = tv2;  pib[2 * BB] = ti2;
  pvb[3 * BB] = tv3;  pib[3 * BB] = ti3;
  pvb[4 * BB] = tv4;  pib[4 * BB] = ti4;
  pvb[5 * BB] = tv5;  pib[5 * BB] = ti5;
  pvb[6 * BB] = tv6;  pib[6 * BB] = ti6;
  pvb[7 * BB] = tv7;  pib[7 * BB] = ti7;
  pvb[8 * BB] = tv8;  pib[8 * BB] = ti8;
  pvb[9 * BB] = tv9;  pib[9 * BB] = ti9;
}

// ---------------------------------------------------------------------------
// Kernel C: merge partial column top-10 lists (sorted desc, early-break),
// count overlap with row top-10, write uncertainty. One thread per column.
// ---------------------------------------------------------------------------
__global__ __launch_bounds__(256) void merge_kernel(const float* __restrict__ pv,
                                                    const int* __restrict__ pi,
                                                    const int* __restrict__ row_top,
                                                    float* __restrict__ out,
                                                    int nch) {
  const int c = blockIdx.x * 256 + threadIdx.x;

  DECL10;

  for (int ch = 0; ch < nch; ++ch) {
    const float* __restrict__ pvb = pv + (size_t)ch * 10 * BB + c;
    const int* __restrict__ pib = pi + (size_t)ch * 10 * BB + c;
#pragma unroll
    for (int j = 0; j < 10; ++j) {
      float vj = pvb[j * BB];
      if (!(vj > tv9)) break;   // sorted desc: rest of this chunk can't qualify
      int idj = pib[j * BB];
      INS10(vj, idj);
    }
  }

  int cnt = 0;
#pragma unroll
  for (int kk = 0; kk < 10; ++kk) {
    int rt = row_top[kk * BB + c];
    cnt += (rt == ti0) + (rt == ti1) + (rt == ti2) + (rt == ti3) + (rt == ti4) +
           (rt == ti5) + (rt == ti6) + (rt == ti7) + (rt == ti8) + (rt == ti9);
  }
  float ne = out[BB + c];
  float ra = (float)cnt * 0.1f;
  out[c] = (1.0f - ra) * 0.5f + 0.5f * ne;
}

// ---------------------------------------------------------------------------
extern "C" void kernel_launch(void* const* d_in, const int* in_sizes, int n_in,
                              void* d_out, int out_size, void* d_ws, size_t ws_size,
                              hipStream_t stream) {
  const float* sim = (const float*)d_in[0];
  float* out = (float*)d_out;

  // Workspace: row_top [10*BB int] | pv [nch*10*BB f32] | pi [nch*10*BB int]
  int nch = 32;
  while (nch > 1) {
    size_t need = (size_t)BB * 10 * 4 + (size_t)nch * BB * 10 * 8;
    if (need <= ws_size) break;
    nch >>= 1;
  }
  int* row_top = (int*)d_ws;
  float* pv = (float*)((char*)d_ws + (size_t)BB * 10 * 4);
  int* pi = (int*)((char*)pv + (size_t)nch * BB * 10 * 4);

  rows_kernel<<<BB, 256, 0, stream>>>(sim, out, row_top);
  dim3 gb(BB / 256, nch);
  cols_partial_kernel<<<gb, 256, 0, stream>>>(sim, pv, pi, BB / nch);
  merge_kernel<<<BB / 256, 256, 0, stream>>>(pv, pi, row_top, out, nch);
}